// Round 3
// baseline (549.919 us; speedup 1.0000x reference)
//
#include <hip/hip_runtime.h>
#include <hip/hip_cooperative_groups.h>

namespace cg = cooperative_groups;

#define L_SEQ 8192
#define DIMN  2048
#define CHUNK 64
#define NCHUNK (L_SEQ / CHUNK)   // 128

typedef float  f32x4  __attribute__((ext_vector_type(4)));
typedef __bf16 bf16x8 __attribute__((ext_vector_type(8)));

__device__ __forceinline__ unsigned short f2bf(float f) {
    unsigned int u = __float_as_uint(f);
    u += 0x7fffu + ((u >> 16) & 1u);          // round-to-nearest-even
    return (unsigned short)(u >> 16);
}

__device__ __forceinline__ float sigmoidf_(float v) {
    return 1.0f / (1.0f + __expf(-v));
}

// ---- Fused scan pipeline (cooperative, 768 blocks x 256 thr, 3 blocks/CU) ----
// Phase 1: blocks 0..255 = per-(chunk, half-channels) local scans (R0 stage1);
//          blocks 256..767 = W fp32->bf16, grid-stride (exactly 8 iters).
// Phase 2: blocks 0..7 = carry prefix over 128 chunks, 4x v[32] wide-issue
//          batches (4 serial round-trips total, not 64 like R2's regression).
// Phase 3: blocks 0..255 = re-scan with correct h_in, emit bf16 (R0 scan_apply).
// grid.sync() between phases; __threadfence for cross-XCD visibility.
__global__ __launch_bounds__(256, 4) void scan_all(
        const float* __restrict__ x, const float* __restrict__ fp,
        const float* __restrict__ W, const float* __restrict__ xml,
        float* __restrict__ carry, unsigned short* __restrict__ Wb,
        unsigned short* __restrict__ xmix) {
    const int b = blockIdx.x;
    const int tid = threadIdx.x;

    // ---------------- Phase 1 ----------------
    if (b < 256) {
        int cg_ = b & 1;                      // channel group (1024 ch each)
        int c   = b >> 1;                     // chunk
        int d4  = cg_ * 256 + tid;            // float4 channel index
        float4 f4 = ((const float4*)fp)[d4];
        float fa = sigmoidf_(f4.x), fb = sigmoidf_(f4.y),
              fc = sigmoidf_(f4.z), fd = sigmoidf_(f4.w);
        float ga = 1.f - fa, gb = 1.f - fb, gc = 1.f - fc, gd = 1.f - fd;
        float ha = 0.f, hb = 0.f, hc = 0.f, hd = 0.f;
        const float4* xp = (const float4*)(x + (size_t)c * CHUNK * DIMN) + d4;
#pragma unroll 8
        for (int t = 0; t < CHUNK; ++t) {
            float4 v = xp[(size_t)t * (DIMN / 4)];
            ha = fmaf(fa, ha, ga * v.x);
            hb = fmaf(fb, hb, gb * v.y);
            hc = fmaf(fc, hc, gc * v.z);
            hd = fmaf(fd, hd, gd * v.w);
        }
        ((float4*)(carry + (size_t)c * DIMN))[d4] = (float4){ha, hb, hc, hd};
    } else {
        // 512 blocks x 256 thr x 8 iters = 1048576 float4s = whole W
        for (int i = (b - 256) * 256 + tid; i < DIMN * DIMN / 4; i += 512 * 256) {
            float4 v = ((const float4*)W)[i];
            ushort4 o;
            o.x = f2bf(v.x); o.y = f2bf(v.y); o.z = f2bf(v.z); o.w = f2bf(v.w);
            ((ushort4*)Wb)[i] = o;
        }
    }
    __threadfence();
    cg::this_grid().sync();

    // ---------------- Phase 2 ----------------
    if (b < 8) {
        int d = b * 256 + tid;                // one channel per thread
        float f = sigmoidf_(fp[d]);
        float fC = f;                          // f^64 via 6 squarings
        fC *= fC; fC *= fC; fC *= fC; fC *= fC; fC *= fC; fC *= fC;
        float h = xml[d];
        for (int c0 = 0; c0 < NCHUNK; c0 += 32) {
            float v[32];
#pragma unroll
            for (int k = 0; k < 32; ++k) v[k] = carry[(size_t)(c0 + k) * DIMN + d];
#pragma unroll
            for (int k = 0; k < 32; ++k) {
                carry[(size_t)(c0 + k) * DIMN + d] = h;   // h_in for chunk c0+k
                h = fmaf(fC, h, v[k]);
            }
        }
    }
    __threadfence();
    cg::this_grid().sync();

    // ---------------- Phase 3 ----------------
    if (b < 256) {
        int cg_ = b & 1;
        int c   = b >> 1;
        int d4  = cg_ * 256 + tid;
        float4 f4 = ((const float4*)fp)[d4];
        float fa = sigmoidf_(f4.x), fb = sigmoidf_(f4.y),
              fc = sigmoidf_(f4.z), fd = sigmoidf_(f4.w);
        float ga = 1.f - fa, gb = 1.f - fb, gc = 1.f - fc, gd = 1.f - fd;
        float4 h0 = ((const float4*)(carry + (size_t)c * DIMN))[d4];
        float ha = h0.x, hb = h0.y, hc = h0.z, hd = h0.w;
        const float4* xp = (const float4*)(x + (size_t)c * CHUNK * DIMN) + d4;
        ushort4* op = (ushort4*)(xmix + (size_t)c * CHUNK * DIMN) + d4;
#pragma unroll 8
        for (int t = 0; t < CHUNK; ++t) {
            float4 v = xp[(size_t)t * (DIMN / 4)];
            ha = fmaf(fa, ha, ga * v.x);
            hb = fmaf(fb, hb, gb * v.y);
            hc = fmaf(fc, hc, gc * v.z);
            hd = fmaf(fd, hd, gd * v.w);
            ushort4 o; o.x = f2bf(ha); o.y = f2bf(hb); o.z = f2bf(hc); o.w = f2bf(hd);
            op[(size_t)t * (DIMN / 4)] = o;
        }
    }
}

// ---- GEMM: C[M][N] = A[M][K] * B[N][K]^T, bf16 in / fp32 out ----
// (R0 version, proven 67-68 us, MfmaUtil ~41%, 0 bank conflicts.)
// 128x256 block tile, BK=64, 4 waves, each wave 64x128 (4x8 of 16x16x32 MFMA).
__global__ __launch_bounds__(256, 2) void gemm_bt(
        const unsigned short* __restrict__ A,
        const unsigned short* __restrict__ B,
        float* __restrict__ C) {
    constexpr int N_ = DIMN, K_ = DIMN;
    constexpr int BK = 64;
    __shared__ __align__(16) unsigned short As[128 * BK];   // 16 KB
    __shared__ __align__(16) unsigned short Bs[256 * BK];   // 32 KB

    int tid  = threadIdx.x;
    int wave = tid >> 6;
    int lane = tid & 63;
    int quad = lane >> 4;
    int l16  = lane & 15;
    int tm = blockIdx.x, tn = blockIdx.y;
    int wm = wave >> 1, wn = wave & 1;

    f32x4 acc[4][8];
#pragma unroll
    for (int i = 0; i < 4; ++i)
#pragma unroll
        for (int j = 0; j < 8; ++j)
            acc[i][j] = (f32x4){0.f, 0.f, 0.f, 0.f};

    const unsigned short* aBase = A + (size_t)(tm * 128) * K_;
    const unsigned short* bBase = B + (size_t)(tn * 256) * K_;

    for (int k0 = 0; k0 < K_; k0 += BK) {
#pragma unroll
        for (int i = 0; i < 4; ++i) {
            int idx = i * 256 + tid;          // A: 1024 chunks
            int row = idx >> 3, slot = idx & 7;
            int cc = slot ^ (row & 7);
            __builtin_amdgcn_global_load_lds(
                (const __attribute__((address_space(1))) void*)(aBase + (size_t)row * K_ + k0 + cc * 8),
                (__attribute__((address_space(3))) void*)(As + idx * 8), 16, 0, 0);
        }
#pragma unroll
        for (int i = 0; i < 8; ++i) {
            int idx = i * 256 + tid;          // B: 2048 chunks
            int row = idx >> 3, slot = idx & 7;
            int cc = slot ^ (row & 7);
            __builtin_amdgcn_global_load_lds(
                (const __attribute__((address_space(1))) void*)(bBase + (size_t)row * K_ + k0 + cc * 8),
                (__attribute__((address_space(3))) void*)(Bs + idx * 8), 16, 0, 0);
        }
        __syncthreads();

#pragma unroll
        for (int kk = 0; kk < BK; kk += 32) {
            bf16x8 af[4], bg[8];
#pragma unroll
            for (int i = 0; i < 4; ++i) {
                int r = wm * 64 + i * 16 + l16;
                int c0 = (kk >> 3) + quad;
                af[i] = *(const bf16x8*)(As + r * BK + ((c0 ^ (r & 7)) << 3));
            }
#pragma unroll
            for (int j = 0; j < 8; ++j) {
                int r = wn * 128 + j * 16 + l16;
                int c0 = (kk >> 3) + quad;
                bg[j] = *(const bf16x8*)(Bs + r * BK + ((c0 ^ (r & 7)) << 3));
            }
#pragma unroll
            for (int i = 0; i < 4; ++i)
#pragma unroll
                for (int j = 0; j < 8; ++j)
                    acc[i][j] = __builtin_amdgcn_mfma_f32_16x16x32_bf16(af[i], bg[j], acc[i][j], 0, 0, 0);
        }
        __syncthreads();
    }

    // Epilogue: C/D layout col = lane&15, row = quad*4 + reg.
#pragma unroll
    for (int i = 0; i < 4; ++i) {
#pragma unroll
        for (int j = 0; j < 8; ++j) {
            int col = tn * 256 + wn * 128 + j * 16 + l16;
#pragma unroll
            for (int r = 0; r < 4; ++r) {
                int row = tm * 128 + wm * 64 + i * 16 + quad * 4 + r;
                C[(size_t)row * N_ + col] = acc[i][j][r];
            }
        }
    }
}

extern "C" void kernel_launch(void* const* d_in, const int* in_sizes, int n_in,
                              void* d_out, int out_size, void* d_ws, size_t ws_size,
                              hipStream_t stream) {
    const float* x   = (const float*)d_in[0];   // [L, D]
    const float* xml = (const float*)d_in[1];   // [D]
    const float* fp  = (const float*)d_in[2];   // [D]
    const float* W   = (const float*)d_in[3];   // [D, D]
    float* out = (float*)d_out;                 // [L, D] fp32

    unsigned short* xmix = (unsigned short*)d_ws;                                      // 32 MB
    unsigned short* Wb   = (unsigned short*)((char*)d_ws + (size_t)L_SEQ * DIMN * 2);  // 8 MB
    float* carry = (float*)((char*)d_ws + (size_t)L_SEQ * DIMN * 2 + (size_t)DIMN * DIMN * 2); // 1 MB

    void* args[] = { (void*)&x, (void*)&fp, (void*)&W, (void*)&xml,
                     (void*)&carry, (void*)&Wb, (void*)&xmix };
    hipLaunchCooperativeKernel(reinterpret_cast<void*>(scan_all),
                               dim3(768), dim3(256), args, 0, stream);
    gemm_bt<<<dim3(L_SEQ / 128, DIMN / 256), 256, 0, stream>>>(xmix, Wb, out);
}

// Round 4
// 202.620 us; speedup vs baseline: 2.7140x; 2.7140x over previous
//
#include <hip/hip_runtime.h>

#define L_SEQ 8192
#define DIMN  2048
#define CHUNK 64
#define NCHUNK (L_SEQ / CHUNK)   // 128

typedef float  f32x4  __attribute__((ext_vector_type(4)));
typedef __bf16 bf16x8 __attribute__((ext_vector_type(8)));

__device__ __forceinline__ unsigned short f2bf(float f) {
    unsigned int u = __float_as_uint(f);
    u += 0x7fffu + ((u >> 16) & 1u);          // round-to-nearest-even
    return (unsigned short)(u >> 16);
}

__device__ __forceinline__ float sigmoidf_(float v) {
    return 1.0f / (1.0f + __expf(-v));
}

// ---- Stage 1 (fused): local chunk scans (blocks 0..255) + W fp32->bf16 (blocks 256..4351)
// (R0 version, unchanged.)
__global__ void stage1(const float* __restrict__ x, const float* __restrict__ fp,
                       const float* __restrict__ W,
                       float* __restrict__ carry, unsigned short* __restrict__ Wb) {
    int b = blockIdx.x;
    if (b < 256) {
        // per-(chunk, 4-channel) local scan with h_in = 0; store carry.
        int cg = b & 1;                       // channel group (1024 ch each)
        int c  = b >> 1;                      // chunk
        int d4 = cg * 256 + threadIdx.x;      // float4 channel index
        float4 f4 = ((const float4*)fp)[d4];
        float fa = sigmoidf_(f4.x), fb = sigmoidf_(f4.y),
              fc = sigmoidf_(f4.z), fd = sigmoidf_(f4.w);
        float ga = 1.f - fa, gb = 1.f - fb, gc = 1.f - fc, gd = 1.f - fd;
        float ha = 0.f, hb = 0.f, hc = 0.f, hd = 0.f;
        const float4* xp = (const float4*)(x + (size_t)c * CHUNK * DIMN) + d4;
#pragma unroll 8
        for (int t = 0; t < CHUNK; ++t) {
            float4 v = xp[(size_t)t * (DIMN / 4)];
            ha = fmaf(fa, ha, ga * v.x);
            hb = fmaf(fb, hb, gb * v.y);
            hc = fmaf(fc, hc, gc * v.z);
            hd = fmaf(fd, hd, gd * v.w);
        }
        ((float4*)(carry + (size_t)c * DIMN))[d4] = (float4){ha, hb, hc, hd};
    } else {
        int i = (b - 256) * 256 + threadIdx.x;     // float4 index into W
        float4 v = ((const float4*)W)[i];
        ushort4 o;
        o.x = f2bf(v.x); o.y = f2bf(v.y); o.z = f2bf(v.z); o.w = f2bf(v.w);
        ((ushort4*)Wb)[i] = o;
    }
}

// ---- Stage 2 (merged prefix + rescan): each block redundantly computes its own
// h_in by chaining h = f^64*h + carry[j] over j < c (identical fma chain to the
// old carry_prefix kernel, so numerics are bit-identical). Carry loads batched
// 16-wide (v[16] float4 in regs): <= 8 L2-hot round-trips for the worst block.
// Removes one kernel launch + one full-grid latency from the critical path.
__global__ void scan_apply(const float* __restrict__ x, const float* __restrict__ fp,
                           const float* __restrict__ xml, const float* __restrict__ carry,
                           unsigned short* __restrict__ xmix) {
    int b = blockIdx.x;
    int cg = b & 1;
    int c  = b >> 1;
    int d4 = cg * 256 + threadIdx.x;
    float4 f4 = ((const float4*)fp)[d4];
    float fa = sigmoidf_(f4.x), fb = sigmoidf_(f4.y),
          fc = sigmoidf_(f4.z), fd = sigmoidf_(f4.w);
    float ga = 1.f - fa, gb = 1.f - fb, gc = 1.f - fc, gd = 1.f - fd;

    // fC = f^64 via 6 squarings (per component) — same as old carry_prefix.
    float Fa = fa, Fb = fb, Fc = fc, Fd = fd;
    Fa *= Fa; Fa *= Fa; Fa *= Fa; Fa *= Fa; Fa *= Fa; Fa *= Fa;
    Fb *= Fb; Fb *= Fb; Fb *= Fb; Fb *= Fb; Fb *= Fb; Fb *= Fb;
    Fc *= Fc; Fc *= Fc; Fc *= Fc; Fc *= Fc; Fc *= Fc; Fc *= Fc;
    Fd *= Fd; Fd *= Fd; Fd *= Fd; Fd *= Fd; Fd *= Fd; Fd *= Fd;

    // h_in(c) = chain over chunks j = 0..c-1, starting from xml.
    float4 m4 = ((const float4*)xml)[d4];
    float ha = m4.x, hb = m4.y, hc = m4.z, hd = m4.w;
    for (int j0 = 0; j0 < c; j0 += 16) {
        float4 v[16];
#pragma unroll
        for (int k = 0; k < 16; ++k)
            if (j0 + k < c)
                v[k] = ((const float4*)(carry + (size_t)(j0 + k) * DIMN))[d4];
#pragma unroll
        for (int k = 0; k < 16; ++k)
            if (j0 + k < c) {
                ha = fmaf(Fa, ha, v[k].x);
                hb = fmaf(Fb, hb, v[k].y);
                hc = fmaf(Fc, hc, v[k].z);
                hd = fmaf(Fd, hd, v[k].w);
            }
    }

    // Rescan chunk c with correct h_in, emit bf16 (R0 body).
    const float4* xp = (const float4*)(x + (size_t)c * CHUNK * DIMN) + d4;
    ushort4* op = (ushort4*)(xmix + (size_t)c * CHUNK * DIMN) + d4;
#pragma unroll 8
    for (int t = 0; t < CHUNK; ++t) {
        float4 v = xp[(size_t)t * (DIMN / 4)];
        ha = fmaf(fa, ha, ga * v.x);
        hb = fmaf(fb, hb, gb * v.y);
        hc = fmaf(fc, hc, gc * v.z);
        hd = fmaf(fd, hd, gd * v.w);
        ushort4 o; o.x = f2bf(ha); o.y = f2bf(hb); o.z = f2bf(hc); o.w = f2bf(hd);
        op[(size_t)t * (DIMN / 4)] = o;
    }
}

// ---- GEMM: C[M][N] = A[M][K] * B[N][K]^T, bf16 in / fp32 out ----
// (R0 version, proven 67-68 us, MfmaUtil ~41%, 0 bank conflicts.)
// 128x256 block tile, BK=64, 4 waves, each wave 64x128 (4x8 of 16x16x32 MFMA).
__global__ __launch_bounds__(256, 2) void gemm_bt(
        const unsigned short* __restrict__ A,
        const unsigned short* __restrict__ B,
        float* __restrict__ C) {
    constexpr int N_ = DIMN, K_ = DIMN;
    constexpr int BK = 64;
    __shared__ __align__(16) unsigned short As[128 * BK];   // 16 KB
    __shared__ __align__(16) unsigned short Bs[256 * BK];   // 32 KB

    int tid  = threadIdx.x;
    int wave = tid >> 6;
    int lane = tid & 63;
    int quad = lane >> 4;
    int l16  = lane & 15;
    int tm = blockIdx.x, tn = blockIdx.y;
    int wm = wave >> 1, wn = wave & 1;

    f32x4 acc[4][8];
#pragma unroll
    for (int i = 0; i < 4; ++i)
#pragma unroll
        for (int j = 0; j < 8; ++j)
            acc[i][j] = (f32x4){0.f, 0.f, 0.f, 0.f};

    const unsigned short* aBase = A + (size_t)(tm * 128) * K_;
    const unsigned short* bBase = B + (size_t)(tn * 256) * K_;

    for (int k0 = 0; k0 < K_; k0 += BK) {
#pragma unroll
        for (int i = 0; i < 4; ++i) {
            int idx = i * 256 + tid;          // A: 1024 chunks
            int row = idx >> 3, slot = idx & 7;
            int cc = slot ^ (row & 7);
            __builtin_amdgcn_global_load_lds(
                (const __attribute__((address_space(1))) void*)(aBase + (size_t)row * K_ + k0 + cc * 8),
                (__attribute__((address_space(3))) void*)(As + idx * 8), 16, 0, 0);
        }
#pragma unroll
        for (int i = 0; i < 8; ++i) {
            int idx = i * 256 + tid;          // B: 2048 chunks
            int row = idx >> 3, slot = idx & 7;
            int cc = slot ^ (row & 7);
            __builtin_amdgcn_global_load_lds(
                (const __attribute__((address_space(1))) void*)(bBase + (size_t)row * K_ + k0 + cc * 8),
                (__attribute__((address_space(3))) void*)(Bs + idx * 8), 16, 0, 0);
        }
        __syncthreads();

#pragma unroll
        for (int kk = 0; kk < BK; kk += 32) {
            bf16x8 af[4], bg[8];
#pragma unroll
            for (int i = 0; i < 4; ++i) {
                int r = wm * 64 + i * 16 + l16;
                int c0 = (kk >> 3) + quad;
                af[i] = *(const bf16x8*)(As + r * BK + ((c0 ^ (r & 7)) << 3));
            }
#pragma unroll
            for (int j = 0; j < 8; ++j) {
                int r = wn * 128 + j * 16 + l16;
                int c0 = (kk >> 3) + quad;
                bg[j] = *(const bf16x8*)(Bs + r * BK + ((c0 ^ (r & 7)) << 3));
            }
#pragma unroll
            for (int i = 0; i < 4; ++i)
#pragma unroll
                for (int j = 0; j < 8; ++j)
                    acc[i][j] = __builtin_amdgcn_mfma_f32_16x16x32_bf16(af[i], bg[j], acc[i][j], 0, 0, 0);
        }
        __syncthreads();
    }

    // Epilogue: C/D layout col = lane&15, row = quad*4 + reg.
#pragma unroll
    for (int i = 0; i < 4; ++i) {
#pragma unroll
        for (int j = 0; j < 8; ++j) {
            int col = tn * 256 + wn * 128 + j * 16 + l16;
#pragma unroll
            for (int r = 0; r < 4; ++r) {
                int row = tm * 128 + wm * 64 + i * 16 + quad * 4 + r;
                C[(size_t)row * N_ + col] = acc[i][j][r];
            }
        }
    }
}

extern "C" void kernel_launch(void* const* d_in, const int* in_sizes, int n_in,
                              void* d_out, int out_size, void* d_ws, size_t ws_size,
                              hipStream_t stream) {
    const float* x   = (const float*)d_in[0];   // [L, D]
    const float* xml = (const float*)d_in[1];   // [D]
    const float* fp  = (const float*)d_in[2];   // [D]
    const float* W   = (const float*)d_in[3];   // [D, D]
    float* out = (float*)d_out;                 // [L, D] fp32

    unsigned short* xmix = (unsigned short*)d_ws;                                      // 32 MB
    unsigned short* Wb   = (unsigned short*)((char*)d_ws + (size_t)L_SEQ * DIMN * 2);  // 8 MB
    float* carry = (float*)((char*)d_ws + (size_t)L_SEQ * DIMN * 2 + (size_t)DIMN * DIMN * 2); // 1 MB

    stage1<<<256 + DIMN * DIMN / 4 / 256, 256, 0, stream>>>(x, fp, W, carry, Wb);
    scan_apply<<<256, 256, 0, stream>>>(x, fp, xml, carry, xmix);
    gemm_bt<<<dim3(L_SEQ / 128, DIMN / 256), 256, 0, stream>>>(xmix, Wb, out);
}